// Round 14
// baseline (5618.982 us; speedup 1.0000x reference)
//
#include <hip/hip_runtime.h>
#include <hip/hip_bf16.h>

#define Tz 512
#define Hz 512
#define NG 8                    // batch groups (group == XCD on the fast path)
#define BG 16                   // batches per group
#define SL 16                   // h-columns per slice
#define NWAVE 6
#define NTHR (NWAVE * 64)
#define SIXH (6 * Hz)
#define HB_U32 (BG * Hz)        // per (parity,group): 16x512 tagged u32 = 32 KB
#define BUF_U32 (2 * NG * HB_U32)   // one exchange buffer: 512 KB
#define META_U32 272                // 16 slot counters + 256 claim flags
#define WS_NEED ((size_t)(2 * BUF_U32 + META_U32) * 4)

typedef __bf16 bf16x8 __attribute__((ext_vector_type(8)));
typedef float f32x4 __attribute__((ext_vector_type(4)));
typedef unsigned int u32;
typedef u32 u32x4v __attribute__((ext_vector_type(4)));

// XCD-local L2 access (L1 bypass): coherent among blocks on the SAME XCD.
__device__ __forceinline__ u32x4v ld_l2_x4(const u32* p) {
  u32x4v r;
  asm volatile("global_load_dwordx4 %0, %1, off sc0" : "=v"(r) : "v"(p) : "memory");
  return r;
}
__device__ __forceinline__ void st_l2_u32(u32* p, u32 v) {
  asm volatile("global_store_dword %0, %1, off sc0" :: "v"(p), "v"(v) : "memory");
}
// Device-scope (MALL): placement-robust path (R7/R8 proven correct).
__device__ __forceinline__ u32x4v ld_mall_x4(const u32* p) {
  u32x4v r;
  asm volatile("global_load_dwordx4 %0, %1, off sc0 sc1" : "=v"(r) : "v"(p) : "memory");
  return r;
}
__device__ __forceinline__ void st_mall_u32(u32* p, u32 v) {
  asm volatile("global_store_dword %0, %1, off sc0 sc1" :: "v"(p), "v"(v) : "memory");
}
// Plain x load (read-only input), asm so no compiler vmcnt(0) lands mid-loop.
__device__ __forceinline__ u32x4v ld_x4(const void* p) {
  u32x4v r;
  asm volatile("global_load_dwordx4 %0, %1, off" : "=v"(r) : "v"(p) : "memory");
  return r;
}
__device__ __forceinline__ void vm_wait0() {
  asm volatile("s_waitcnt vmcnt(0)" ::: "memory");
  __builtin_amdgcn_sched_barrier(0);
}
__device__ __forceinline__ void bar_lds() {   // LDS-only barrier: VMEM floats
  asm volatile("s_waitcnt lgkmcnt(0)" ::: "memory");
  __builtin_amdgcn_s_barrier();
  __builtin_amdgcn_sched_barrier(0);
}
__device__ __forceinline__ float sigf(float x) { return 1.f / (1.f + __expf(-x)); }
__device__ __forceinline__ float tanh_f(float x) { return 2.f / (1.f + __expf(-2.f * x)) - 1.f; }
__device__ __forceinline__ float uf(u32 b) { return __builtin_bit_cast(float, b); }
__device__ __forceinline__ u32 pk2(float a, float b) {
  unsigned short lo = __builtin_bit_cast(unsigned short, (__bf16)a);
  unsigned short hi = __builtin_bit_cast(unsigned short, (__bf16)b);
  return (u32)lo | ((u32)hi << 16);
}

// Sentinel tags (0xFFFF != any t) in both buffers; zero counters/flags.
__global__ void lstm_init(u32* ws, int n) {
  int i = blockIdx.x * blockDim.x + threadIdx.x;
  if (i < n) ws[i] = (i < 2 * BUF_U32) ? 0xFFFF0000u : 0u;
}

__global__ __launch_bounds__(NTHR) void lstm_main(
    const float* __restrict__ x, const int* __restrict__ lens,
    const float* __restrict__ Wg, const float* __restrict__ bg,
    float* __restrict__ out, u32* __restrict__ hbF, u32* __restrict__ hbS,
    u32* __restrict__ meta, int use_dyn)
{
  const int tid = threadIdx.x;
  const int l   = tid & 63;
  const int w   = tid >> 6;          // wave id = gate chunk (0..4 gates, 5 = px5)
  const int wg  = blockIdx.x;
  const int oct = l >> 4;
  const int lm  = l & 15;

  __shared__ __align__(16) char xs[2][BG * Hz * 2];   // 2 x 16 KB bf16 x-tiles
  __shared__ __align__(16) char hs[BG * Hz * 2];      // 16 KB bf16 h-tile
  __shared__ float gs[NWAVE][BG][SL];                 // 6 KB gate exchange
  __shared__ char pad_1cu[28672];                     // force 1 block/CU (84 KB)
  __shared__ int sh_pair;

  // ---- placement-aware (gi,si): gi == actual XCD; CAS table keeps it bijective ----
  int gi, si;
  if (use_dyn) {
    if (tid == 0) {
      u32 xcd;
      asm volatile("s_getreg_b32 %0, hwreg(HW_REG_XCC_ID)" : "=s"(xcd));
      xcd &= 7;
      u32* cnt   = meta;
      u32* flags = meta + 16;
      u32 slot = atomicAdd(&cnt[xcd], 1u);
      int pair = -1;
      if (slot < 32u && atomicCAS(&flags[xcd * 32 + slot], 0u, 1u) == 0u)
        pair = (int)(xcd * 32 + slot);
      if (pair < 0) {                 // escape: claim any free pair (correct, slow)
        for (int k = 0; k < 4096 && pair < 0; ++k) {
          int idx = (wg * 37 + k) & 255;
          if (__hip_atomic_load(&flags[idx], __ATOMIC_RELAXED, __HIP_MEMORY_SCOPE_AGENT) == 0u
              && atomicCAS(&flags[idx], 0u, 1u) == 0u) pair = idx;
        }
        if (pair < 0) pair = wg & 255;   // unreachable; keeps kernel finite
      }
      sh_pair = pair;
      if (lens[0] == -2147483647) pad_1cu[0] = 1;   // keep pad allocated
    }
    __syncthreads();
    gi = sh_pair >> 5; si = sh_pair & 31;
  } else {
    gi = wg & 7; si = wg >> 3;
    if (tid == 0 && lens[0] == -2147483647) pad_1cu[0] = 1;
    __syncthreads();
  }

  // ---- resident W fragments: wave w owns W[:, w*512 + si*16 + (0..15)] ----
  const int colg = w * Hz + si * SL + lm;
  bf16x8 wf[16];
#pragma unroll
  for (int s = 0; s < 16; ++s)
#pragma unroll
    for (int j = 0; j < 8; ++j)
      wf[s][j] = (__bf16)Wg[(size_t)(32 * s + 8 * oct + j) * SIXH + colg];
  const float bv = bg[colg];
  const float bias = (w < 5) ? 2.f * bv : bv;   // ref adds b_in in BOTH projections

  const int erow = tid >> 4;   // batch within group (tid<256 view)
  const int ecol = tid & 15;
  float cc = 0.f;
  int mylen = 0;
  if (tid < 256) mylen = lens[gi * BG + erow];

  u32x4v f[8];                 // x(t+1) payload bits
  u32 pnd_off = 0, pnd_tag = 0;   // deferred MALL shadow publish

  auto stage_x = [&](const u32x4v* fx, int par) {
#pragma unroll
    for (int Q = 0; Q < 4; ++Q) {
      u32x4v v = { pk2(uf(fx[2*Q][0]),   uf(fx[2*Q][1])),
                   pk2(uf(fx[2*Q][2]),   uf(fx[2*Q][3])),
                   pk2(uf(fx[2*Q+1][0]), uf(fx[2*Q+1][1])),
                   pk2(uf(fx[2*Q+1][2]), uf(fx[2*Q+1][3])) };
      int byte = (erow * 1024 + ecol * 64 + 16 * Q) ^ ((erow & 7) << 4);
      *(u32x4v*)(&xs[par][byte]) = v;
    }
  };

  // ---- prologue: stage x(0); preload x(1) ----
  if (tid < 256) {
    const char* x0 = (const char*)(x + ((size_t)(gi * BG + erow) * Tz + 0) * Hz + ecol * 32);
#pragma unroll
    for (int q = 0; q < 8; ++q) f[q] = ld_x4(x0 + 16 * q);
    vm_wait0();
    stage_x(f, 0);
    const char* x1 = (const char*)(x + ((size_t)(gi * BG + erow) * Tz + 1) * Hz + ecol * 32);
#pragma unroll
    for (int q = 0; q < 8; ++q) f[q] = ld_x4(x1 + 16 * q);
    vm_wait0();
  }
  __syncthreads();

  for (int t = 0; t < Tz; ++t) {
    const int parW = t & 1, parR = (t + 1) & 1;
    const bool do_h = (t > 0) && (tid < 256);
    const u32 roff = (u32)(((parR * NG + gi) * HB_U32) + erow * Hz + ecol * 32);
    const u32* hpF = hbF + roff;
    const u32* hpS = hbS + roff;
    u32x4v hv4[8];
    // ---- [A] stage x(t+1) from f ----
    if (tid < 256 && t + 1 < Tz) stage_x(f, parR);
    // ---- [B0] issue x(t+2) loads (HBM latency hidden until [D]) ----
    if (tid < 256 && t + 2 < Tz) {
      const char* xr = (const char*)(x + ((size_t)(gi * BG + erow) * Tz + (t + 2)) * Hz + ecol * 32);
#pragma unroll
      for (int q = 0; q < 8; ++q) f[q] = ld_x4(xr + 16 * q);
    }
    // ---- [B1] visibility delay, then speculative tagged h(t-1) read ----
    if (t > 0) {
      if (use_dyn) asm volatile("s_sleep 2" ::: "memory");   // L2 ~fast
      else         asm volatile("s_sleep 8" ::: "memory");   // MALL (R12-tuned)
    }
    if (do_h) {
      if (use_dyn) {
#pragma unroll
        for (int q = 0; q < 8; ++q) hv4[q] = ld_l2_x4(hpF + 4 * q);
      } else {
#pragma unroll
        for (int q = 0; q < 8; ++q) hv4[q] = ld_mall_x4(hpF + 4 * q);
      }
    }
    // ---- [C] x-half MFMAs while reads fly ----
    f32x4 acc0; acc0[0] = bias; acc0[1] = bias; acc0[2] = bias; acc0[3] = bias;
    f32x4 acc1; acc1[0] = 0.f; acc1[1] = 0.f; acc1[2] = 0.f; acc1[3] = 0.f;
    {
      const char* xb = xs[parW];
#pragma unroll
      for (int s = 0; s < 16; ++s) {
        int byte = (lm * 1024 + 64 * s + 16 * oct) ^ ((lm & 7) << 4);
        bf16x8 a = *(const bf16x8*)(xb + byte);
        if (s & 1) acc1 = __builtin_amdgcn_mfma_f32_16x16x32_bf16(a, wf[s], acc1, 0, 0, 0);
        else       acc0 = __builtin_amdgcn_mfma_f32_16x16x32_bf16(a, wf[s], acc0, 0, 0, 0);
      }
    }
    // ---- [D] single full drain; validate; retry stale chunks (L2 -> MALL) ----
    if (tid < 256) vm_wait0();
    if (do_h) {
      const u32 etag = (u32)(t - 1);
      u32 badmask = 0;
#pragma unroll
      for (int q = 0; q < 8; ++q) {
        bool b = false;
#pragma unroll
        for (int j = 0; j < 4; ++j) b |= ((hv4[q][j] >> 16) != etag);
        badmask |= (u32)b << q;
      }
      int r = 0;
      while (__builtin_expect(badmask != 0, 0)) {
        if (r >= 2) asm volatile("s_sleep 1" ::: "memory");
#pragma unroll
        for (int q = 0; q < 8; ++q)
          if (badmask & (1u << q))
            hv4[q] = (!use_dyn) ? ld_mall_x4(hpF + 4 * q)
                   : (r < 6)    ? ld_l2_x4(hpF + 4 * q)
                                : ld_mall_x4(hpS + 4 * q);   // shadow fallback
        vm_wait0();
        u32 nb = 0;
#pragma unroll
        for (int q = 0; q < 8; ++q) {
          bool b = false;
#pragma unroll
          for (int j = 0; j < 4; ++j) b |= ((hv4[q][j] >> 16) != etag);
          nb |= (u32)b << q;
        }
        badmask = nb;
        if (++r > 1000000) break;               // finite on catastrophe only
      }
      // strip tags via v_perm; 4x16B swizzled LDS stores
#pragma unroll
      for (int k2 = 0; k2 < 4; ++k2) {
        u32x4v o;
#pragma unroll
        for (int m = 0; m < 4; ++m) {
          int c = 8 * k2 + 2 * m;
          o[m] = __builtin_amdgcn_perm(hv4[(c + 1) >> 2][(c + 1) & 3],
                                       hv4[c >> 2][c & 3], 0x05040100u);
        }
        int byte = (erow * 1024 + ecol * 64 + 16 * k2) ^ ((erow & 7) << 4);
        *(u32x4v*)(&hs[byte]) = o;
      }
    }
    // ---- [E] deferred MALL shadow publish of step t-1 (ack never stalls us) ----
    if (use_dyn && t > 0 && tid < 256) st_mall_u32(hbS + pnd_off, pnd_tag);
    bar_lds();   // barrier-1 (LDS-only): h tile + next x tile ready
    // ---- [F] h-half MFMAs; gates to LDS ----
    if (w < 5 && t > 0) {
#pragma unroll
      for (int s = 0; s < 16; ++s) {
        int byte = (lm * 1024 + 64 * s + 16 * oct) ^ ((lm & 7) << 4);
        bf16x8 a = *(const bf16x8*)(hs + byte);
        if (s & 1) acc1 = __builtin_amdgcn_mfma_f32_16x16x32_bf16(a, wf[s], acc1, 0, 0, 0);
        else       acc0 = __builtin_amdgcn_mfma_f32_16x16x32_bf16(a, wf[s], acc0, 0, 0, 0);
      }
    }
    {
      f32x4 g = acc0 + acc1;
#pragma unroll
      for (int r2 = 0; r2 < 4; ++r2) gs[w][oct * 4 + r2][lm] = g[r2];
    }
    bar_lds();   // barrier-2 (LDS-only): gates ready
    // ---- [G] cell + highway; publish tagged h (fast path); out ----
    if (tid < 256) {
      float g0 = gs[0][erow][ecol], g1 = gs[1][erow][ecol], g2 = gs[2][erow][ecol];
      float g3 = gs[3][erow][ecol], g4 = gs[4][erow][ecol], px5 = gs[5][erow][ecol];
      float ig = sigf(g0), fg = sigf(g1), mg = tanh_f(g2), og = sigf(g3), hg = sigf(g4);
      float cn = ig * mg + fg * cc;
      float ot = og * tanh_f(cn);
      ot = hg * ot + (1.f - hg) * px5;
      bool act = t < mylen;
      float hv = act ? ot : 0.f;
      cc = act ? cn : 0.f;
      u32 tagged = ((u32)t << 16) | (u32)__builtin_bit_cast(unsigned short, (__bf16)hv);
      u32 woff = (u32)(((parW * NG + gi) * HB_U32) + erow * Hz + si * SL + ecol);
      if (use_dyn) {
        st_l2_u32(hbF + woff, tagged);   // XCD-local L2: peers see it in ~200cy
        pnd_off = woff; pnd_tag = tagged;   // shadow deferred to next [E]
      } else {
        st_mall_u32(hbF + woff, tagged);
      }
      out[((size_t)(gi * BG + erow) * Tz + t) * Hz + si * SL + ecol] = hv;
    }
  }
}

extern "C" void kernel_launch(void* const* d_in, const int* in_sizes, int n_in,
                              void* d_out, int out_size, void* d_ws, size_t ws_size,
                              hipStream_t stream) {
  const float* x  = (const float*)d_in[0];
  const int* lens = (const int*)d_in[1];      // jax x64 disabled -> int32
  const float* Wg = (const float*)d_in[2];
  const float* bg = (const float*)d_in[3];
  float* out = (float*)d_out;                 // reference output dtype: float32

  u32* hbF = (u32*)d_ws;
  const int use_dyn = (ws_size >= WS_NEED) ? 1 : 0;
  u32* hbS  = use_dyn ? (hbF + BUF_U32)     : hbF;
  u32* meta = use_dyn ? (hbF + 2 * BUF_U32) : hbF;
  const int nInit = use_dyn ? (2 * BUF_U32 + META_U32) : BUF_U32;

  hipLaunchKernelGGL(lstm_init, dim3((nInit + 255) / 256), dim3(256), 0, stream,
                     hbF, nInit);
  // 256 blocks x 84KB LDS -> exactly 1 block/CU -> 32 blocks per XCD; group
  // membership discovered via HW_REG_XCC_ID, bijective via CAS claim table.
  hipLaunchKernelGGL(lstm_main, dim3(256), dim3(NTHR), 0, stream,
                     x, lens, Wg, bg, out, hbF, hbS, meta, use_dyn);
}

// Round 15
// 2191.674 us; speedup vs baseline: 2.5638x; 2.5638x over previous
//
#include <hip/hip_runtime.h>
#include <hip/hip_bf16.h>

#define Tz 512
#define Hz 512
#define NG 8                    // batch groups
#define BG 16                   // batches per group
#define SL 16                   // h-columns per slice
#define NWAVE 6
#define NTHR (NWAVE * 64)
#define SIXH (6 * Hz)
#define HB_U32 (BG * Hz)        // per (parity,group): 16x512 tagged u32 = 32 KB
#define WS_U32 (2 * NG * HB_U32)    // exchange buffer: 512 KB

typedef __bf16 bf16x8 __attribute__((ext_vector_type(8)));
typedef float f32x4 __attribute__((ext_vector_type(4)));
typedef unsigned int u32;
typedef u32 u32x4v __attribute__((ext_vector_type(4)));

// Device-scope (MALL) tagged access. R7+R14 lessons: cross-CU exchange must
// use sc0 sc1 — L2-local (sc0-only) publish never becomes visible to peers.
__device__ __forceinline__ u32x4v ld_coh_x4(const u32* p) {
  u32x4v r;
  asm volatile("global_load_dwordx4 %0, %1, off sc0 sc1" : "=v"(r) : "v"(p) : "memory");
  return r;
}
__device__ __forceinline__ void st_coh_u32(u32* p, u32 v) {
  asm volatile("global_store_dword %0, %1, off sc0 sc1" :: "v"(p), "v"(v) : "memory");
}
__device__ __forceinline__ void vm_wait0() {
  asm volatile("s_waitcnt vmcnt(0)" ::: "memory");
  __builtin_amdgcn_sched_barrier(0);
}
// Raw LDS-only barrier (lets the x(t+2) prefetch + publish stores float).
__device__ __forceinline__ void bar_lds() {
  asm volatile("s_waitcnt lgkmcnt(0)" ::: "memory");
  __builtin_amdgcn_s_barrier();
  __builtin_amdgcn_sched_barrier(0);
}
__device__ __forceinline__ float sigf(float x) { return 1.f / (1.f + __expf(-x)); }
__device__ __forceinline__ float tanh_f(float x) { return 2.f / (1.f + __expf(-2.f * x)) - 1.f; }
__device__ __forceinline__ u32 pk_bf16(float a, float b) {
  unsigned short lo = __builtin_bit_cast(unsigned short, (__bf16)a);
  unsigned short hi = __builtin_bit_cast(unsigned short, (__bf16)b);
  return (u32)lo | ((u32)hi << 16);
}

// Sentinel tags (0xFFFF != any t in [0,512)).
__global__ void lstm_init(u32* ws) {
  int i = blockIdx.x * blockDim.x + threadIdx.x;   // WS_U32 threads
  ws[i] = 0xFFFF0000u;
}

__global__ __launch_bounds__(NTHR) void lstm_main(
    const float* __restrict__ x, const int* __restrict__ lens,
    const float* __restrict__ Wg, const float* __restrict__ bg,
    float* __restrict__ out, u32* __restrict__ hb)
{
  const int tid = threadIdx.x;
  const int l   = tid & 63;
  const int w   = tid >> 6;          // wave id = gate chunk (0..4 gates, 5 = px5)
  const int wg  = blockIdx.x;
  const int gi  = wg & 7;            // batch group
  const int si  = wg >> 3;           // column slice 0..31
  const int oct = l >> 4;
  const int lm  = l & 15;

  __shared__ __align__(16) char xs[2][BG * Hz * 2];   // 2 x 16 KB bf16 x-tiles
  __shared__ __align__(16) char hs[BG * Hz * 2];      // 16 KB bf16 h-tile
  __shared__ float gs[NWAVE][BG][SL];                 // 6 KB gate exchange

  // ---- resident W fragments: wave w owns W[:, w*512 + si*16 + (0..15)] ----
  const int colg = w * Hz + si * SL + lm;
  bf16x8 wf[16];
#pragma unroll
  for (int s = 0; s < 16; ++s) {
#pragma unroll
    for (int j = 0; j < 8; ++j) {
      wf[s][j] = (__bf16)Wg[(size_t)(32 * s + 8 * oct + j) * SIXH + colg];
    }
  }
  const float bv = bg[colg];
  const float bias = (w < 5) ? 2.f * bv : bv;   // ref adds b_in in BOTH projections

  const int erow = tid >> 4;   // batch within group (tid<256 view)
  const int ecol = tid & 15;
  float cc = 0.f;
  int mylen = 0;
  if (tid < 256) mylen = lens[gi * BG + erow];

  float4 f[8];   // x(t+1) payload, loaded during step t-1 (or prologue)

  // ---- prologue: stage x(0); issue x(1) into f ----
  if (tid < 256) {
    const float4* xr = (const float4*)(x + ((size_t)(gi * BG + erow) * Tz + 0) * Hz + ecol * 32);
    float4 f0[8];
#pragma unroll
    for (int q = 0; q < 8; ++q) f0[q] = xr[q];
#pragma unroll
    for (int Q = 0; Q < 4; ++Q) {
      u32x4v v = { pk_bf16(f0[2*Q].x, f0[2*Q].y),   pk_bf16(f0[2*Q].z, f0[2*Q].w),
                   pk_bf16(f0[2*Q+1].x, f0[2*Q+1].y), pk_bf16(f0[2*Q+1].z, f0[2*Q+1].w) };
      int byte = (erow * 1024 + ecol * 64 + 16 * Q) ^ ((erow & 7) << 4);
      *(u32x4v*)(&xs[0][byte]) = v;
    }
    const float4* xr1 = (const float4*)(x + ((size_t)(gi * BG + erow) * Tz + 1) * Hz + ecol * 32);
#pragma unroll
    for (int q = 0; q < 8; ++q) f[q] = xr1[q];
  }
  __syncthreads();

  for (int t = 0; t < Tz; ++t) {
    const bool do_h = (t > 0) && (tid < 256);
    const u32* hp = hb + ((size_t)((t + 1) & 1) * NG + gi) * HB_U32 + erow * Hz + ecol * 32;
    u32x4v hv4[8];
    // ---- [A] stage x(t+1) from f (LDS + VALU) ----
    if (tid < 256 && t + 1 < Tz) {
#pragma unroll
      for (int Q = 0; Q < 4; ++Q) {
        u32x4v v = { pk_bf16(f[2*Q].x, f[2*Q].y),   pk_bf16(f[2*Q].z, f[2*Q].w),
                     pk_bf16(f[2*Q+1].x, f[2*Q+1].y), pk_bf16(f[2*Q+1].z, f[2*Q+1].w) };
        int byte = (erow * 1024 + ecol * 64 + 16 * Q) ^ ((erow & 7) << 4);
        *(u32x4v*)(&xs[(t + 1) & 1][byte]) = v;
      }
    }
    // ---- [B] visibility delay: sample the MALL AFTER peers' publishes are
    //      visible AND after our own store-acks retired (R12 confirmed the
    //      mechanism at sleep 8; sleep 32 sized to the ~0.9us visibility) ----
    if (t > 0) {
      asm volatile("s_sleep 32" ::: "memory");   // ~2048 cy ~= 0.85 us
    }
    if (do_h) {
#pragma unroll
      for (int q = 0; q < 8; ++q) hv4[q] = ld_coh_x4(hp + 4 * q);
    }
    // ---- [C] x-half MFMAs while the reads fly ----
    f32x4 acc0; acc0[0] = bias; acc0[1] = bias; acc0[2] = bias; acc0[3] = bias;
    f32x4 acc1; acc1[0] = 0.f; acc1[1] = 0.f; acc1[2] = 0.f; acc1[3] = 0.f;
    {
      const char* xb = xs[t & 1];
#pragma unroll
      for (int s = 0; s < 16; ++s) {
        int byte = (lm * 1024 + 64 * s + 16 * oct) ^ ((lm & 7) << 4);
        bf16x8 a = *(const bf16x8*)(xb + byte);
        if (s & 1) acc1 = __builtin_amdgcn_mfma_f32_16x16x32_bf16(a, wf[s], acc1, 0, 0, 0);
        else       acc0 = __builtin_amdgcn_mfma_f32_16x16x32_bf16(a, wf[s], acc0, 0, 0, 0);
      }
    }
    // ---- [D] single full drain; validate tags; retry ONLY stale 16B chunks ----
    if (tid < 256) vm_wait0();
    if (do_h) {
      const u32 etag = (u32)(t - 1);
      u32 badmask = 0;
#pragma unroll
      for (int q = 0; q < 8; ++q) {
        bool b = false;
#pragma unroll
        for (int j = 0; j < 4; ++j) b |= ((hv4[q][j] >> 16) != etag);
        badmask |= (u32)b << q;
      }
      int guard = 0;
      while (__builtin_expect(badmask != 0, 0)) {   // straggler peers only
#pragma unroll
        for (int q = 0; q < 8; ++q)
          if (badmask & (1u << q)) hv4[q] = ld_coh_x4(hp + 4 * q);
        vm_wait0();
        u32 nb = 0;
#pragma unroll
        for (int q = 0; q < 8; ++q) {
          bool b = false;
#pragma unroll
          for (int j = 0; j < 4; ++j) b |= ((hv4[q][j] >> 16) != etag);
          nb |= (u32)b << q;
        }
        badmask = nb;
        if (++guard > 1000000) break;               // finite on catastrophe only
      }
      // strip tags via v_perm (1 op per packed pair), 4x16B swizzled LDS stores
#pragma unroll
      for (int k2 = 0; k2 < 4; ++k2) {
        u32x4v o;
#pragma unroll
        for (int m = 0; m < 4; ++m) {
          int c = 8 * k2 + 2 * m;
          o[m] = __builtin_amdgcn_perm(hv4[(c + 1) >> 2][(c + 1) & 3],
                                       hv4[c >> 2][c & 3], 0x05040100u);
        }
        int byte = (erow * 1024 + ecol * 64 + 16 * k2) ^ ((erow & 7) << 4);
        *(u32x4v*)(&hs[byte]) = o;
      }
    }
    // ---- [E] issue x(t+2) (floats across both raw barriers; drains at the
    //      next step's [D] vm_wait0 with a full step of cover) ----
    if (tid < 256 && t + 2 < Tz) {
      const float4* xr = (const float4*)(x + ((size_t)(gi * BG + erow) * Tz + (t + 2)) * Hz + ecol * 32);
#pragma unroll
      for (int q = 0; q < 8; ++q) f[q] = xr[q];
    }
    bar_lds();   // barrier-1 (LDS-only): h tile + next x tile ready
    // ---- [F] h-half MFMAs; gates to LDS ----
    if (w < 5 && t > 0) {
#pragma unroll
      for (int s = 0; s < 16; ++s) {
        int byte = (lm * 1024 + 64 * s + 16 * oct) ^ ((lm & 7) << 4);
        bf16x8 a = *(const bf16x8*)(hs + byte);
        if (s & 1) acc1 = __builtin_amdgcn_mfma_f32_16x16x32_bf16(a, wf[s], acc1, 0, 0, 0);
        else       acc0 = __builtin_amdgcn_mfma_f32_16x16x32_bf16(a, wf[s], acc0, 0, 0, 0);
      }
    }
    {
      f32x4 g = acc0 + acc1;
#pragma unroll
      for (int r = 0; r < 4; ++r) gs[w][oct * 4 + r][lm] = g[r];
    }
    bar_lds();   // barrier-2 (LDS-only): gates ready
    // ---- [G] elementwise cell + highway; publish tagged h FIRST (stores float) ----
    if (tid < 256) {
      float g0 = gs[0][erow][ecol], g1 = gs[1][erow][ecol], g2 = gs[2][erow][ecol];
      float g3 = gs[3][erow][ecol], g4 = gs[4][erow][ecol], px5 = gs[5][erow][ecol];
      float ig = sigf(g0), fg = sigf(g1), mg = tanh_f(g2), og = sigf(g3), hg = sigf(g4);
      float cn = ig * mg + fg * cc;
      float ot = og * tanh_f(cn);
      ot = hg * ot + (1.f - hg) * px5;
      bool act = t < mylen;
      float hv = act ? ot : 0.f;
      cc = act ? cn : 0.f;
      u32 tagged = ((u32)t << 16) | (u32)__builtin_bit_cast(unsigned short, (__bf16)hv);
      u32* hwp = hb + ((size_t)(t & 1) * NG + gi) * HB_U32 + erow * Hz + si * SL + ecol;
      st_coh_u32(hwp, tagged);                    // tag+payload, self-validating
      out[((size_t)(gi * BG + erow) * Tz + t) * Hz + si * SL + ecol] = hv;
      // no vmcnt, no atomics: consumers validate tags and retry stragglers
    }
  }
}

extern "C" void kernel_launch(void* const* d_in, const int* in_sizes, int n_in,
                              void* d_out, int out_size, void* d_ws, size_t ws_size,
                              hipStream_t stream) {
  const float* x  = (const float*)d_in[0];
  const int* lens = (const int*)d_in[1];      // jax x64 disabled -> int32
  const float* Wg = (const float*)d_in[2];
  const float* bg = (const float*)d_in[3];
  float* out = (float*)d_out;                 // reference output dtype: float32
  u32* hb = (u32*)d_ws;                       // 512KB tagged h exchange

  hipLaunchKernelGGL(lstm_init, dim3(WS_U32 / 256), dim3(256), 0, stream, hb);
  hipLaunchKernelGGL(lstm_main, dim3(256), dim3(NTHR), 0, stream,
                     x, lens, Wg, bg, out, hb);
}

// Round 16
// 1907.430 us; speedup vs baseline: 2.9458x; 1.1490x over previous
//
#include <hip/hip_runtime.h>
#include <hip/hip_bf16.h>

#define Tz 512
#define Hz 512
#define NG 8                    // batch groups
#define BG 16                   // batches per group
#define SL 16                   // h-columns per slice
#define NWAVE 6
#define NTHR (NWAVE * 64)
#define SIXH (6 * Hz)
#define HB_U32 (BG * Hz)        // per (parity,group): 16x512 tagged u32 = 32 KB
#define WS_U32 (2 * NG * HB_U32)    // exchange buffer: 512 KB

typedef __bf16 bf16x8 __attribute__((ext_vector_type(8)));
typedef float f32x4 __attribute__((ext_vector_type(4)));
typedef unsigned int u32;
typedef u32 u32x4v __attribute__((ext_vector_type(4)));

// Device-scope (MALL) tagged access. R7+R14: cross-CU exchange must be sc0 sc1.
__device__ __forceinline__ u32x4v ld_coh_x4(const u32* p) {
  u32x4v r;
  asm volatile("global_load_dwordx4 %0, %1, off sc0 sc1" : "=v"(r) : "v"(p) : "memory");
  return r;
}
__device__ __forceinline__ void st_coh_u32(u32* p, u32 v) {
  asm volatile("global_store_dword %0, %1, off sc0 sc1" :: "v"(p), "v"(v) : "memory");
}
__device__ __forceinline__ void vm_wait0() {
  asm volatile("s_waitcnt vmcnt(0)" ::: "memory");
  __builtin_amdgcn_sched_barrier(0);
}
// Raw LDS-only barrier (lets the x(t+2) prefetch + publish stores float).
__device__ __forceinline__ void bar_lds() {
  asm volatile("s_waitcnt lgkmcnt(0)" ::: "memory");
  __builtin_amdgcn_s_barrier();
  __builtin_amdgcn_sched_barrier(0);
}
__device__ __forceinline__ float sigf(float x) { return 1.f / (1.f + __expf(-x)); }
__device__ __forceinline__ float tanh_f(float x) { return 2.f / (1.f + __expf(-2.f * x)) - 1.f; }
__device__ __forceinline__ u32 pk_bf16(float a, float b) {
  unsigned short lo = __builtin_bit_cast(unsigned short, (__bf16)a);
  unsigned short hi = __builtin_bit_cast(unsigned short, (__bf16)b);
  return (u32)lo | ((u32)hi << 16);
}

// Sentinel tags (0xFFFF != any t in [0,512)).
__global__ void lstm_init(u32* ws) {
  int i = blockIdx.x * blockDim.x + threadIdx.x;   // WS_U32 threads
  ws[i] = 0xFFFF0000u;
}

__global__ __launch_bounds__(NTHR) void lstm_main(
    const float* __restrict__ x, const int* __restrict__ lens,
    const float* __restrict__ Wg, const float* __restrict__ bg,
    float* __restrict__ out, u32* __restrict__ hb)
{
  const int tid = threadIdx.x;
  const int l   = tid & 63;
  const int w   = tid >> 6;          // wave id = gate chunk (0..4 gates, 5 = px5)
  const int wg  = blockIdx.x;
  const int gi  = wg & 7;            // batch group
  const int si  = wg >> 3;           // column slice 0..31
  const int oct = l >> 4;
  const int lm  = l & 15;

  __shared__ __align__(16) char xs[2][BG * Hz * 2];   // 2 x 16 KB bf16 x-tiles
  __shared__ __align__(16) char hs[BG * Hz * 2];      // 16 KB bf16 h-tile
  __shared__ float gs[NWAVE][BG][SL];                 // 6 KB gate exchange

  // ---- resident W fragments: wave w owns W[:, w*512 + si*16 + (0..15)] ----
  const int colg = w * Hz + si * SL + lm;
  bf16x8 wf[16];
#pragma unroll
  for (int s = 0; s < 16; ++s) {
#pragma unroll
    for (int j = 0; j < 8; ++j) {
      wf[s][j] = (__bf16)Wg[(size_t)(32 * s + 8 * oct + j) * SIXH + colg];
    }
  }
  const float bv = bg[colg];
  const float bias = (w < 5) ? 2.f * bv : bv;   // ref adds b_in in BOTH projections

  const int erow = tid >> 4;   // batch within group (tid<256 view)
  const int ecol = tid & 15;
  float cc = 0.f;
  int mylen = 0;
  if (tid < 256) mylen = lens[gi * BG + erow];

  float4 f[8];   // x(t+1) payload, loaded during step t-1 (or prologue)

  // ---- prologue: stage x(0); issue x(1) into f ----
  if (tid < 256) {
    const float4* xr = (const float4*)(x + ((size_t)(gi * BG + erow) * Tz + 0) * Hz + ecol * 32);
    float4 f0[8];
#pragma unroll
    for (int q = 0; q < 8; ++q) f0[q] = xr[q];
#pragma unroll
    for (int Q = 0; Q < 4; ++Q) {
      u32x4v v = { pk_bf16(f0[2*Q].x, f0[2*Q].y),   pk_bf16(f0[2*Q].z, f0[2*Q].w),
                   pk_bf16(f0[2*Q+1].x, f0[2*Q+1].y), pk_bf16(f0[2*Q+1].z, f0[2*Q+1].w) };
      int byte = (erow * 1024 + ecol * 64 + 16 * Q) ^ ((erow & 7) << 4);
      *(u32x4v*)(&xs[0][byte]) = v;
    }
    const float4* xr1 = (const float4*)(x + ((size_t)(gi * BG + erow) * Tz + 1) * Hz + ecol * 32);
#pragma unroll
    for (int q = 0; q < 8; ++q) f[q] = xr1[q];
  }
  __syncthreads();

  for (int t = 0; t < Tz; ++t) {
    const bool do_h = (t > 0) && (tid < 256);
    const u32* hp = hb + ((size_t)((t + 1) & 1) * NG + gi) * HB_U32 + erow * Hz + ecol * 32;
    u32x4v hv4[8];
    // ---- [A] stage x(t+1) from f (LDS + VALU: ~0.15us natural delay) ----
    if (tid < 256 && t + 1 < Tz) {
#pragma unroll
      for (int Q = 0; Q < 4; ++Q) {
        u32x4v v = { pk_bf16(f[2*Q].x, f[2*Q].y),   pk_bf16(f[2*Q].z, f[2*Q].w),
                     pk_bf16(f[2*Q+1].x, f[2*Q+1].y), pk_bf16(f[2*Q+1].z, f[2*Q+1].w) };
        int byte = (erow * 1024 + ecol * 64 + 16 * Q) ^ ((erow & 7) << 4);
        *(u32x4v*)(&xs[(t + 1) & 1][byte]) = v;
      }
    }
    // ---- [B] visibility delay (R12-proven optimum): total pre-read delay
    //      ~0.36us puts the MALL sample past peers' publish visibility ----
    if (t > 0) {
      asm volatile("s_sleep 8" ::: "memory");   // ~512 cy ~= 0.21 us
    }
    if (do_h) {
#pragma unroll
      for (int q = 0; q < 8; ++q) hv4[q] = ld_coh_x4(hp + 4 * q);
    }
    // ---- [C] x-half MFMAs while the reads fly ----
    f32x4 acc0; acc0[0] = bias; acc0[1] = bias; acc0[2] = bias; acc0[3] = bias;
    f32x4 acc1; acc1[0] = 0.f; acc1[1] = 0.f; acc1[2] = 0.f; acc1[3] = 0.f;
    {
      const char* xb = xs[t & 1];
#pragma unroll
      for (int s = 0; s < 16; ++s) {
        int byte = (lm * 1024 + 64 * s + 16 * oct) ^ ((lm & 7) << 4);
        bf16x8 a = *(const bf16x8*)(xb + byte);
        if (s & 1) acc1 = __builtin_amdgcn_mfma_f32_16x16x32_bf16(a, wf[s], acc1, 0, 0, 0);
        else       acc0 = __builtin_amdgcn_mfma_f32_16x16x32_bf16(a, wf[s], acc0, 0, 0, 0);
      }
    }
    // ---- [D] single full drain; validate tags; retry ONLY stale 16B chunks ----
    if (tid < 256) vm_wait0();
    if (do_h) {
      const u32 etag = (u32)(t - 1);
      u32 badmask = 0;
#pragma unroll
      for (int q = 0; q < 8; ++q) {
        bool b = false;
#pragma unroll
        for (int j = 0; j < 4; ++j) b |= ((hv4[q][j] >> 16) != etag);
        badmask |= (u32)b << q;
      }
      int guard = 0;
      while (__builtin_expect(badmask != 0, 0)) {   // straggler peers only
        if (guard > 0) asm volatile("s_sleep 1" ::: "memory");   // backoff: let
        // the straggler's store land instead of burning MALL BW on re-reads
#pragma unroll
        for (int q = 0; q < 8; ++q)
          if (badmask & (1u << q)) hv4[q] = ld_coh_x4(hp + 4 * q);
        vm_wait0();
        u32 nb = 0;
#pragma unroll
        for (int q = 0; q < 8; ++q) {
          bool b = false;
#pragma unroll
          for (int j = 0; j < 4; ++j) b |= ((hv4[q][j] >> 16) != etag);
          nb |= (u32)b << q;
        }
        badmask = nb;
        if (++guard > 1000000) break;               // finite on catastrophe only
      }
      // strip tags via v_perm (1 op per packed pair), 4x16B swizzled LDS stores
#pragma unroll
      for (int k2 = 0; k2 < 4; ++k2) {
        u32x4v o;
#pragma unroll
        for (int m = 0; m < 4; ++m) {
          int c = 8 * k2 + 2 * m;
          o[m] = __builtin_amdgcn_perm(hv4[(c + 1) >> 2][(c + 1) & 3],
                                       hv4[c >> 2][c & 3], 0x05040100u);
        }
        int byte = (erow * 1024 + ecol * 64 + 16 * k2) ^ ((erow & 7) << 4);
        *(u32x4v*)(&hs[byte]) = o;
      }
    }
    // ---- [E] issue x(t+2) (floats across both raw barriers; drains at the
    //      next step's [D] vm_wait0 with a full step of cover) ----
    if (tid < 256 && t + 2 < Tz) {
      const float4* xr = (const float4*)(x + ((size_t)(gi * BG + erow) * Tz + (t + 2)) * Hz + ecol * 32);
#pragma unroll
      for (int q = 0; q < 8; ++q) f[q] = xr[q];
    }
    bar_lds();   // barrier-1 (LDS-only): h tile + next x tile ready
    // ---- [F] h-half MFMAs; gates to LDS ----
    if (w < 5 && t > 0) {
#pragma unroll
      for (int s = 0; s < 16; ++s) {
        int byte = (lm * 1024 + 64 * s + 16 * oct) ^ ((lm & 7) << 4);
        bf16x8 a = *(const bf16x8*)(hs + byte);
        if (s & 1) acc1 = __builtin_amdgcn_mfma_f32_16x16x32_bf16(a, wf[s], acc1, 0, 0, 0);
        else       acc0 = __builtin_amdgcn_mfma_f32_16x16x32_bf16(a, wf[s], acc0, 0, 0, 0);
      }
    }
    {
      f32x4 g = acc0 + acc1;
#pragma unroll
      for (int r = 0; r < 4; ++r) gs[w][oct * 4 + r][lm] = g[r];
    }
    bar_lds();   // barrier-2 (LDS-only): gates ready
    // ---- [G] elementwise cell + highway; publish tagged h (stores float) ----
    if (tid < 256) {
      float g0 = gs[0][erow][ecol], g1 = gs[1][erow][ecol], g2 = gs[2][erow][ecol];
      float g3 = gs[3][erow][ecol], g4 = gs[4][erow][ecol], px5 = gs[5][erow][ecol];
      float ig = sigf(g0), fg = sigf(g1), mg = tanh_f(g2), og = sigf(g3), hg = sigf(g4);
      float cn = ig * mg + fg * cc;
      float ot = og * tanh_f(cn);
      ot = hg * ot + (1.f - hg) * px5;
      bool act = t < mylen;
      float hv = act ? ot : 0.f;
      cc = act ? cn : 0.f;
      u32 tagged = ((u32)t << 16) | (u32)__builtin_bit_cast(unsigned short, (__bf16)hv);
      u32* hwp = hb + ((size_t)(t & 1) * NG + gi) * HB_U32 + erow * Hz + si * SL + ecol;
      st_coh_u32(hwp, tagged);                    // tag+payload, self-validating
      out[((size_t)(gi * BG + erow) * Tz + t) * Hz + si * SL + ecol] = hv;
      // no vmcnt, no atomics: consumers validate tags and retry stragglers
    }
  }
}

extern "C" void kernel_launch(void* const* d_in, const int* in_sizes, int n_in,
                              void* d_out, int out_size, void* d_ws, size_t ws_size,
                              hipStream_t stream) {
  const float* x  = (const float*)d_in[0];
  const int* lens = (const int*)d_in[1];      // jax x64 disabled -> int32
  const float* Wg = (const float*)d_in[2];
  const float* bg = (const float*)d_in[3];
  float* out = (float*)d_out;                 // reference output dtype: float32
  u32* hb = (u32*)d_ws;                       // 512KB tagged h exchange

  hipLaunchKernelGGL(lstm_init, dim3(WS_U32 / 256), dim3(256), 0, stream, hb);
  hipLaunchKernelGGL(lstm_main, dim3(256), dim3(NTHR), 0, stream,
                     x, lens, Wg, bg, out, hb);
}